// Round 1
// 200.110 us; speedup vs baseline: 1.0320x; 1.0320x over previous
//
#include <hip/hip_runtime.h>

typedef float f32x4 __attribute__((ext_vector_type(4)));
typedef short s16x8 __attribute__((ext_vector_type(8)));
typedef unsigned short us4 __attribute__((ext_vector_type(4)));

#define MFMA16(a, b, c) __builtin_amdgcn_mfma_f32_16x16x32_bf16(a, b, c, 0, 0, 0)

// async global->LDS DMA, 16B per lane. LDS dest must be wave-uniform base + lane*16.
#define GLOAD_LDS16(gp, lp) __builtin_amdgcn_global_load_lds( \
    (__attribute__((address_space(1))) void*)(gp),            \
    (__attribute__((address_space(3))) void*)(lp), 16, 0, 0)

__device__ __forceinline__ unsigned short f2bf(float f) {
    union { float f; unsigned u; } v; v.f = f;
    unsigned r = v.u + 0x7fffu + ((v.u >> 16) & 1u);   // RNE truncate to bf16
    return (unsigned short)(r >> 16);
}

// ---------------------------------------------------------------------------
// m97-style GEMM core, 128x128 tile: C += A[128xK] @ B[128xK]^T.
// 256 thr = 4 waves in 2x2 quadrants of 64x64, each wave 4x4 16x16x32 MFMAs.
// ---------------------------------------------------------------------------
__device__ __forceinline__ void gemm_core128(
    const unsigned short* __restrict__ Ab, size_t Astride,
    const unsigned short* __restrict__ Bb, size_t Bstride,
    int K, unsigned short* As, unsigned short* Bs,
    int t, f32x4 acc[4][4])
{
    const int wave = t >> 6, lane = t & 63;
    const int c = lane & 15, quad = lane >> 4;
    const int wm = (wave >> 1) * 64, wn = (wave & 1) * 64;
    const int srow = t >> 2;
    const int scol = (t & 3) * 8;

    for (int k0 = 0; k0 < K; k0 += 32) {
        __syncthreads();
        const unsigned short* ga = Ab + (size_t)srow * Astride + k0 + scol;
        const unsigned short* gb = Bb + (size_t)srow * Bstride + k0 + scol;
        GLOAD_LDS16(ga,                 As + t * 8);
        GLOAD_LDS16(ga + 64 * Astride,  As + 2048 + t * 8);
        GLOAD_LDS16(gb,                 Bs + t * 8);
        GLOAD_LDS16(gb + 64 * Bstride,  Bs + 2048 + t * 8);
        __syncthreads();

        s16x8 af[4], bf[4];
        #pragma unroll
        for (int i = 0; i < 4; i++)
            af[i] = *(const s16x8*)(As + (wm + i * 16 + c) * 32 + quad * 8);
        #pragma unroll
        for (int i = 0; i < 4; i++)
            bf[i] = *(const s16x8*)(Bs + (wn + i * 16 + c) * 32 + quad * 8);
        #pragma unroll
        for (int mt = 0; mt < 4; mt++)
            #pragma unroll
            for (int nt = 0; nt < 4; nt++)
                acc[mt][nt] = MFMA16(af[mt], bf[nt], acc[mt][nt]);
    }
}

// ---------------------------------------------------------------------------
// Kernel 1: convert x -> bf16 row-major; W{q,k,v} -> bf16 transposed [n][k]
// via 64x64 LDS-transpose tiles (coalesced reads AND writes — the old scalar
// 1KB-strided writes were ~32x RMW-inflated on HBM); zero the l accumulator.
// Grid 4320: [0,4096) x-convert, [4096,4288) 192 weight tiles, [4288,4320) lg.
// ---------------------------------------------------------------------------
__global__ __launch_bounds__(256) void k_convert(
    const float* __restrict__ x, const float* __restrict__ wq,
    const float* __restrict__ wk, const float* __restrict__ wv,
    unsigned short* __restrict__ xbf, unsigned short* __restrict__ wt,
    float* __restrict__ lg)
{
    __shared__ __align__(16) unsigned short lt[64][72];   // 64x64 tile, padded

    int bid = blockIdx.x, t = threadIdx.x;
    if (bid < 4096) {
        int gid = bid * 256 + t;
        float4 v = ((const float4*)x)[gid];
        us4 o = { f2bf(v.x), f2bf(v.y), f2bf(v.z), f2bf(v.w) };
        ((us4*)xbf)[gid] = o;
    } else if (bid < 4288) {
        int idx = bid - 4096;
        int w = idx >> 6;                    // 0=q 1=k 2=v
        int tile = idx & 63;
        int tk = tile >> 3, tn = tile & 7;   // 8x8 tiles of 64x64 over [512][512]
        const float* src = ((w == 0) ? wq : (w == 1) ? wk : wv)
                         + (size_t)(tk * 64) * 512 + tn * 64;

        // read 64x64 f32 coalesced, stage transposed as bf16
        int row = t >> 2;
        int c0 = (t & 3) * 16;
        const float4* s = (const float4*)(src + (size_t)row * 512 + c0);
        #pragma unroll
        for (int q = 0; q < 4; q++) {
            float4 v = s[q];
            lt[c0 + q * 4 + 0][row] = f2bf(v.x);
            lt[c0 + q * 4 + 1][row] = f2bf(v.y);
            lt[c0 + q * 4 + 2][row] = f2bf(v.z);
            lt[c0 + q * 4 + 3][row] = f2bf(v.w);
        }
        __syncthreads();

        // write out wt[n][k] coalesced, 32B per thread
        int n = t >> 2;
        int k0 = (t & 3) * 16;
        s16x8 a = *(const s16x8*)&lt[n][k0];
        s16x8 b = *(const s16x8*)&lt[n][k0 + 8];
        unsigned short* dst = wt + (((size_t)(w * 512 + tn * 64 + n)) << 9)
                                 + tk * 64 + k0;
        *(s16x8*)dst = a;
        *(s16x8*)(dst + 8) = b;
    } else {
        lg[(bid - 4288) * 256 + t] = 0.f;
    }
}

// ---------------------------------------------------------------------------
// Kernel 2: QKV projection. [8192x512] @ [1536x512]^T. Grid (64,12).
// ---------------------------------------------------------------------------
__global__ __launch_bounds__(256) void k_proj(
    const unsigned short* __restrict__ xbf, const unsigned short* __restrict__ wt,
    unsigned short* __restrict__ qbf, unsigned short* __restrict__ kbf,
    unsigned short* __restrict__ vtbf)
{
    __shared__ __align__(16) unsigned short As[128 * 32];
    __shared__ __align__(16) unsigned short Bs[128 * 32];

    int t = threadIdx.x;
    int m0 = blockIdx.x * 128, n0 = blockIdx.y * 128;
    f32x4 acc[4][4] = {};

    gemm_core128(xbf + (size_t)m0 * 512, 512, wt + (size_t)n0 * 512, 512,
                 512, As, Bs, t, acc);

    int wave = t >> 6, lane = t & 63, c = lane & 15, quad = lane >> 4;
    int wm = (wave >> 1) * 64, wn = (wave & 1) * 64;
    int sel = blockIdx.y >> 2;                    // 0=q 1=k 2=v

    if (sel < 2) {
        unsigned short* dst = sel ? kbf : qbf;
        int ncol0 = n0 - sel * 512;
        #pragma unroll
        for (int mt = 0; mt < 4; mt++) {
            #pragma unroll
            for (int nt = 0; nt < 4; nt++) {
                int col = ncol0 + wn + nt * 16 + c;
                #pragma unroll
                for (int r = 0; r < 4; r++) {
                    int rw = m0 + wm + mt * 16 + quad * 4 + r;
                    dst[(size_t)rw * 512 + col] = f2bf(acc[mt][nt][r]);
                }
            }
        }
    } else {
        #pragma unroll
        for (int mt = 0; mt < 4; mt++) {
            int rw0 = m0 + wm + mt * 16 + quad * 4;
            int bb = rw0 >> 11, nn = rw0 & 2047;
            #pragma unroll
            for (int nt = 0; nt < 4; nt++) {
                int d = (n0 - 1024) + wn + nt * 16 + c;
                us4 pk = { f2bf(acc[mt][nt][0]), f2bf(acc[mt][nt][1]),
                           f2bf(acc[mt][nt][2]), f2bf(acc[mt][nt][3]) };
                *(us4*)(vtbf + ((size_t)(bb * 512 + d)) * 2048 + nn) = pk;
            }
        }
    }
}

// ---------------------------------------------------------------------------
// score body: S = Q@K^T (128x128 tile), P = exp(S*scale) -> bf16, l atomics.
// ---------------------------------------------------------------------------
__device__ __forceinline__ void score_body(
    const unsigned short* __restrict__ qbf, const unsigned short* __restrict__ kbf,
    unsigned short* __restrict__ pbf, float* __restrict__ lg,
    int b, int m0, int n0, int t, unsigned short* As, unsigned short* Bs)
{
    f32x4 acc[4][4] = {};
    gemm_core128(qbf + (size_t)(b * 2048 + m0) * 512, 512,
                 kbf + (size_t)(b * 2048 + n0) * 512, 512,
                 512, As, Bs, t, acc);

    int wave = t >> 6, lane = t & 63, c = lane & 15, quad = lane >> 4;
    int wm = (wave >> 1) * 64, wn = (wave & 1) * 64;
    const float scale = 0.044194173824159216f;    // 1/sqrt(512)

    #pragma unroll
    for (int mt = 0; mt < 4; mt++) {
        #pragma unroll
        for (int r = 0; r < 4; r++) {
            int row = m0 + wm + mt * 16 + quad * 4 + r;
            float rs = 0.f;
            #pragma unroll
            for (int nt = 0; nt < 4; nt++) {
                float p = __expf(acc[mt][nt][r] * scale);
                rs += p;
                pbf[(size_t)(b * 2048 + row) * 2048 + n0 + wn + nt * 16 + c] = f2bf(p);
            }
            rs += __shfl_xor(rs, 1, 16);
            rs += __shfl_xor(rs, 2, 16);
            rs += __shfl_xor(rs, 4, 16);
            rs += __shfl_xor(rs, 8, 16);
            if (c == 0) atomicAdd(&lg[b * 2048 + row], rs);
        }
    }
}

// ---------------------------------------------------------------------------
// prior: one WAVE per (b,i) row — no LDS, no barriers, no atomics.
// sigma = x_row.Ws via 6-shfl reduce; lane owns 32 cols interleaved as
// j = u*256 + lane*4 + v so every float4 store is a coalesced 1KB segment.
// inv_norm prefactor cancels in the row normalization.
// ---------------------------------------------------------------------------
__device__ __forceinline__ void prior_wave(
    const float* __restrict__ x, const float* __restrict__ wsv,
    float* __restrict__ pout, int row, int lane)
{
    const float4* xr = (const float4*)(x + (size_t)row * 512);
    const float4* wr = (const float4*)wsv;
    float4 a0 = xr[lane * 2],     b0 = wr[lane * 2];
    float4 a1 = xr[lane * 2 + 1], b1 = wr[lane * 2 + 1];
    float part = a0.x * b0.x + a0.y * b0.y + a0.z * b0.z + a0.w * b0.w
               + a1.x * b1.x + a1.y * b1.y + a1.z * b1.z + a1.w * b1.w;
    #pragma unroll
    for (int o = 32; o; o >>= 1) part += __shfl_xor(part, o, 64);
    float sigma = part;
    float inv2 = 0.5f / (sigma * sigma);

    int i = row & 2047;
    float g[32];
    float sum = 0.f;
    #pragma unroll
    for (int u = 0; u < 8; u++) {
        #pragma unroll
        for (int v = 0; v < 4; v++) {
            float d = (float)(u * 256 + lane * 4 + v - i);
            float e = __expf(-(d * d) * inv2);
            g[u * 4 + v] = e;
            sum += e;
        }
    }
    #pragma unroll
    for (int o = 32; o; o >>= 1) sum += __shfl_xor(sum, o, 64);
    float inv = 1.0f / sum;

    float4* pr = (float4*)(pout + (size_t)row * 2048);
    #pragma unroll
    for (int u = 0; u < 8; u++) {
        float4 o4 = { g[u * 4] * inv, g[u * 4 + 1] * inv,
                      g[u * 4 + 2] * inv, g[u * 4 + 3] * inv };
        pr[u * 64 + lane] = o4;
    }
}

// ---------------------------------------------------------------------------
// Kernel 3a (ws path): merged score + prior. Grid 3072 1D:
// blocks [0,1024) score (b = bid>>8, m-tile = bid&15, n-tile = (bid>>4)&15),
// blocks [1024,3072) prior, 4 rows/block (wave-per-row). Prior writes overlap
// score compute (pout is disjoint from all scratch when scratch lives in d_ws).
// ---------------------------------------------------------------------------
__global__ __launch_bounds__(256) void k_score_prior(
    const unsigned short* __restrict__ qbf, const unsigned short* __restrict__ kbf,
    unsigned short* __restrict__ pbf, float* __restrict__ lg,
    const float* __restrict__ x, const float* __restrict__ wsv,
    float* __restrict__ pout)
{
    __shared__ __align__(16) unsigned short As[128 * 32];
    __shared__ __align__(16) unsigned short Bs[128 * 32];

    int bid = blockIdx.x, t = threadIdx.x;
    if (bid < 1024) {
        int b = bid >> 8, r = bid & 255;
        score_body(qbf, kbf, pbf, lg, b, (r & 15) * 128, (r >> 4) * 128, t, As, Bs);
    } else {
        int row = (bid - 1024) * 4 + (t >> 6);
        prior_wave(x, wsv, pout, row, t & 63);
    }
}

// ---------------------------------------------------------------------------
// Kernel 3b (fallback): standalone score. Grid (16,16,4).
// ---------------------------------------------------------------------------
__global__ __launch_bounds__(256) void k_score(
    const unsigned short* __restrict__ qbf, const unsigned short* __restrict__ kbf,
    unsigned short* __restrict__ pbf, float* __restrict__ lg)
{
    __shared__ __align__(16) unsigned short As[128 * 32];
    __shared__ __align__(16) unsigned short Bs[128 * 32];
    score_body(qbf, kbf, pbf, lg, blockIdx.z,
               blockIdx.x * 128, blockIdx.y * 128, threadIdx.x, As, Bs);
}

// ---------------------------------------------------------------------------
// Kernel 4: output. Per batch: O = P @ Vt^T scaled by 1/l. 128x64 tile,
// grid (16,8,4) = 512 blocks (2 blocks/CU). Wave quadrants 2x2 of 64x32:
// acc[4][2], per iter 3 staging + 6 ds_read + 8 MFMA, K=2048 -> 64 iters.
// ---------------------------------------------------------------------------
__global__ __launch_bounds__(256) void k_out(
    const unsigned short* __restrict__ pbf, const unsigned short* __restrict__ vtbf,
    const float* __restrict__ lg, float* __restrict__ zout)
{
    __shared__ __align__(16) unsigned short As[128 * 32];   // P tile
    __shared__ __align__(16) unsigned short Bs[64 * 32];    // Vt tile
    __shared__ float invl[128];

    int t = threadIdx.x;
    int b = blockIdx.z;
    int m0 = blockIdx.x * 128, n0 = blockIdx.y * 64;

    if (t < 128) invl[t] = 1.0f / lg[b * 2048 + m0 + t];

    const unsigned short* Ab = pbf + (size_t)(b * 2048 + m0) * 2048;
    const unsigned short* Bb = vtbf + (size_t)(b * 512 + n0) * 2048;

    const int wave = t >> 6, lane = t & 63;
    const int c = lane & 15, quad = lane >> 4;
    const int wm = (wave >> 1) * 64, wn = (wave & 1) * 32;
    const int srow = t >> 2;
    const int scol = (t & 3) * 8;

    f32x4 acc[4][2] = {};

    for (int k0 = 0; k0 < 2048; k0 += 32) {
        __syncthreads();
        const unsigned short* ga = Ab + (size_t)srow * 2048 + k0 + scol;
        GLOAD_LDS16(ga,             As + t * 8);
        GLOAD_LDS16(ga + 64 * 2048, As + 2048 + t * 8);
        GLOAD_LDS16(Bb + (size_t)srow * 2048 + k0 + scol, Bs + t * 8);
        __syncthreads();

        s16x8 af[4], bf[2];
        #pragma unroll
        for (int i = 0; i < 4; i++)
            af[i] = *(const s16x8*)(As + (wm + i * 16 + c) * 32 + quad * 8);
        #pragma unroll
        for (int i = 0; i < 2; i++)
            bf[i] = *(const s16x8*)(Bs + (wn + i * 16 + c) * 32 + quad * 8);
        #pragma unroll
        for (int mt = 0; mt < 4; mt++)
            #pragma unroll
            for (int nt = 0; nt < 2; nt++)
                acc[mt][nt] = MFMA16(af[mt], bf[nt], acc[mt][nt]);
    }

    #pragma unroll
    for (int mt = 0; mt < 4; mt++) {
        #pragma unroll
        for (int nt = 0; nt < 2; nt++) {
            #pragma unroll
            for (int r = 0; r < 4; r++) {
                int row = wm + mt * 16 + quad * 4 + r;
                zout[(size_t)(b * 2048 + m0 + row) * 512 + n0 + wn + nt * 16 + c]
                    = acc[mt][nt][r] * invl[row];
            }
        }
    }
}

// ---------------------------------------------------------------------------
// Kernel 5 (fallback): standalone prior. Grid 2048, 4 rows/block.
// ---------------------------------------------------------------------------
__global__ __launch_bounds__(256) void k_prior(
    const float* __restrict__ x, const float* __restrict__ wsv,
    float* __restrict__ pout)
{
    int row = blockIdx.x * 4 + (threadIdx.x >> 6);
    prior_wave(x, wsv, pout, row, threadIdx.x & 63);
}

// ---------------------------------------------------------------------------
extern "C" void kernel_launch(void* const* d_in, const int* in_sizes, int n_in,
                              void* d_out, int out_size, void* d_ws, size_t ws_size,
                              hipStream_t stream)
{
    const float* x  = (const float*)d_in[0];
    const float* wq = (const float*)d_in[1];
    const float* wk = (const float*)d_in[2];
    const float* wv = (const float*)d_in[3];
    const float* ws = (const float*)d_in[4];

    float* zout = (float*)d_out;                       // (4,2048,512)
    float* pout = zout + (size_t)4 * 2048 * 512;       // (4,2048,2048) = 67.1 MB

    // Scratch needs: xbf 4.19M + wt 0.79M + q/k/vt 3*4.19M + pbf 16.78M
    // ushorts + lg 8192 f32 = 68.7 MB.
    const size_t need = ((size_t)4194304 + 786432 + 3 * 4194304 + 16777216) * 2
                        + 8192 * 4;

    if (ws_size >= need) {
        // ---- ws path: all scratch in d_ws; pout free -> prior overlaps score
        unsigned short* base = (unsigned short*)d_ws;
        unsigned short* xbf  = base;
        unsigned short* wt   = xbf  + (size_t)4194304;
        unsigned short* qbf  = wt   + (size_t)786432;
        unsigned short* kbf  = qbf  + (size_t)4194304;
        unsigned short* vtbf = kbf  + (size_t)4194304;
        unsigned short* pbf  = vtbf + (size_t)4194304;
        float*          lg   = (float*)(pbf + (size_t)16777216);

        k_convert<<<dim3(4320), dim3(256), 0, stream>>>(x, wq, wk, wv, xbf, wt, lg);
        k_proj       <<<dim3(64, 12),   dim3(256), 0, stream>>>(xbf, wt, qbf, kbf, vtbf);
        k_score_prior<<<dim3(3072),     dim3(256), 0, stream>>>(qbf, kbf, pbf, lg, x, ws, pout);
        k_out        <<<dim3(16, 8, 4), dim3(256), 0, stream>>>(pbf, vtbf, lg, zout);
    } else {
        // ---- fallback: round-3 layout inside pout (prior runs last)
        unsigned short* base = (unsigned short*)pout;
        unsigned short* pbf  = base;                        // 16,777,216
        unsigned short* qbf  = base + (size_t)16777216;
        unsigned short* kbf  = qbf  + (size_t)4194304;
        unsigned short* vtbf = kbf  + (size_t)4194304;
        float*          lg   = (float*)(vtbf + (size_t)4194304);
        unsigned short* xbf  = base;                        // overlaps pbf (ok)
        unsigned short* wt   = base + (size_t)4194304;      // overlaps pbf (ok)

        k_convert<<<dim3(4320), dim3(256), 0, stream>>>(x, wq, wk, wv, xbf, wt, lg);
        k_proj  <<<dim3(64, 12),    dim3(256), 0, stream>>>(xbf, wt, qbf, kbf, vtbf);
        k_score <<<dim3(16, 16, 4), dim3(256), 0, stream>>>(qbf, kbf, pbf, lg);
        k_out   <<<dim3(16, 8, 4),  dim3(256), 0, stream>>>(pbf, vtbf, lg, zout);
        k_prior <<<dim3(2048),      dim3(256), 0, stream>>>(x, ws, pout);
    }
}